// Round 1
// baseline (397.781 us; speedup 1.0000x reference)
//
#include <hip/hip_runtime.h>

typedef unsigned short u16;
typedef __attribute__((ext_vector_type(8))) short short8;   // 8 bf16 (4 VGPRs) - MFMA A/B frag
typedef __attribute__((ext_vector_type(4))) float f4;       // MFMA C/D frag
typedef __attribute__((ext_vector_type(8))) unsigned short us8;

// ---------- helpers ----------
__device__ __forceinline__ u16 f2bf(float f) {              // RNE fp32 -> bf16
    unsigned u = __float_as_uint(f);
    u += 0x7FFFu + ((u >> 16) & 1u);
    return (u16)(u >> 16);
}
__device__ __forceinline__ float bf2f(u16 h) {
    return __uint_as_float(((unsigned)h) << 16);
}

#define GLD16(gp, lp) __builtin_amdgcn_global_load_lds( \
    (const __attribute__((address_space(1))) void*)(gp), \
    (__attribute__((address_space(3))) void*)(lp), 16, 0, 0)

// s = (d_head^0.5)^(-0.25) = 8^(-0.25)
#define SCALE_S 0.594603557501360533f

// ---------- fp32 -> bf16 (8 elems/thread) ----------
__global__ __launch_bounds__(256) void convert_f32_bf16(const float* __restrict__ in,
                                                        u16* __restrict__ out) {
    const size_t i = (size_t)blockIdx.x * 256 + threadIdx.x;
    const float4* p = (const float4*)in + i * 2;
    float4 a = p[0], b = p[1];
    us8 r;
    r[0] = f2bf(a.x); r[1] = f2bf(a.y); r[2] = f2bf(a.z); r[3] = f2bf(a.w);
    r[4] = f2bf(b.x); r[5] = f2bf(b.y); r[6] = f2bf(b.z); r[7] = f2bf(b.w);
    *(us8*)(out + i * 8) = r;
}

// ---------- transpose + convert: out[n][k] = bf16(W[k][n]), 1024x1024 ----------
__global__ __launch_bounds__(256) void transpose_convert(const float* __restrict__ W,
                                                         u16* __restrict__ out) {
    __shared__ float tile[32][33];
    const int tx = threadIdx.x, ty = threadIdx.y;   // 32 x 8
    const int x = blockIdx.x * 32 + tx;
#pragma unroll
    for (int i = 0; i < 4; ++i) {
        const int y = blockIdx.y * 32 + ty + i * 8;
        tile[ty + i * 8][tx] = W[(size_t)y * 1024 + x];
    }
    __syncthreads();
#pragma unroll
    for (int i = 0; i < 4; ++i) {
        const int yo = blockIdx.x * 32 + ty + i * 8;  // out row (= W col)
        const int xo = blockIdx.y * 32 + tx;          // out col (= W row)
        out[(size_t)yo * 1024 + xo] = f2bf(tile[tx][ty + i * 8]);
    }
}

__global__ void concat_bias(const float* __restrict__ bq, const float* __restrict__ bv,
                            float* __restrict__ bqv) {
    const int i = blockIdx.x * 256 + threadIdx.x;   // 0..2047
    bqv[i] = (i < 1024) ? bq[i] : bv[i - 1024];
}

// ---------- MFMA GEMM: C = A[M,K] * BT[N,K]^T + bias ----------
// mode 0: fp32 store (final output).  mode 1: fused QV epilogue -- cols < N/2:
// row-softmax over 64-wide head chunk * s -> qsOut (bf16); cols >= N/2: v -> vOut (bf16).
__global__ __launch_bounds__(256) void gemm_bt(
    const u16* __restrict__ A, const u16* __restrict__ BT,
    const float* __restrict__ bias, float* __restrict__ C,
    u16* __restrict__ qsOut, u16* __restrict__ vOut,
    int N, int K, int mode,
    long long Ab, long long Bb, long long Cb)
{
    __shared__ u16 As[128 * 64];
    __shared__ u16 Bs[128 * 64];
    const int t = threadIdx.x;
    const int w = t >> 6, l = t & 63;
    const int quad = l >> 4, lrow = l & 15;
    const int z = blockIdx.z;
    A  += (size_t)z * Ab;
    BT += (size_t)z * Bb;
    const int m0 = blockIdx.x * 128;
    const int n0 = blockIdx.y * 128;
    const int wm = (w & 1) * 64, wn = (w >> 1) * 64;

    const int srow = t >> 3;          // staging row within 32-row pass
    const int scol = (t & 7) * 8;     // staging col (8 bf16 = 16B)

    f4 acc[4][4] = {};

    for (int k0 = 0; k0 < K; k0 += 64) {
#pragma unroll
        for (int p = 0; p < 4; ++p) {
            const int row = p * 32 + srow;
            GLD16(A  + (size_t)(m0 + row) * K + k0 + scol, &As[row * 64 + scol]);
            GLD16(BT + (size_t)(n0 + row) * K + k0 + scol, &Bs[row * 64 + scol]);
        }
        __syncthreads();
#pragma unroll
        for (int kk = 0; kk < 2; ++kk) {
            const int koff = kk * 32 + quad * 8;
            short8 a[4], b[4];
#pragma unroll
            for (int i = 0; i < 4; ++i)
                a[i] = *(const short8*)&As[(wm + i * 16 + lrow) * 64 + koff];
#pragma unroll
            for (int j = 0; j < 4; ++j)
                b[j] = *(const short8*)&Bs[(wn + j * 16 + lrow) * 64 + koff];
#pragma unroll
            for (int i = 0; i < 4; ++i)
#pragma unroll
                for (int j = 0; j < 4; ++j)
                    acc[i][j] = __builtin_amdgcn_mfma_f32_16x16x32_bf16(a[i], b[j], acc[i][j], 0, 0, 0);
        }
        __syncthreads();
    }

    const int colb = n0 + wn + lrow;
    const float b0 = bias[colb], b1 = bias[colb + 16], b2 = bias[colb + 32], b3 = bias[colb + 48];

    if (mode == 0) {
        C += (size_t)z * Cb;
#pragma unroll
        for (int i = 0; i < 4; ++i) {
            const int rbase = m0 + wm + i * 16 + quad * 4;
#pragma unroll
            for (int r = 0; r < 4; ++r) {
                float* cp = C + (size_t)(rbase + r) * N + colb;
                cp[0]  = acc[i][0][r] + b0;
                cp[16] = acc[i][1][r] + b1;
                cp[32] = acc[i][2][r] + b2;
                cp[48] = acc[i][3][r] + b3;
            }
        }
    } else {
        const bool isQ = (n0 + wn) < (N >> 1);   // wave-uniform
#pragma unroll
        for (int i = 0; i < 4; ++i) {
            const int rbase = m0 + wm + i * 16 + quad * 4;
#pragma unroll
            for (int r = 0; r < 4; ++r) {
                float v0 = acc[i][0][r] + b0;
                float v1 = acc[i][1][r] + b1;
                float v2 = acc[i][2][r] + b2;
                float v3 = acc[i][3][r] + b3;
                if (isQ) {
                    // softmax over this row's 64-wide head chunk (lives in 16 lanes x 4 frags)
                    float m = fmaxf(fmaxf(v0, v1), fmaxf(v2, v3));
                    m = fmaxf(m, __shfl_xor(m, 1));
                    m = fmaxf(m, __shfl_xor(m, 2));
                    m = fmaxf(m, __shfl_xor(m, 4));
                    m = fmaxf(m, __shfl_xor(m, 8));
                    float e0 = __expf(v0 - m), e1 = __expf(v1 - m);
                    float e2 = __expf(v2 - m), e3 = __expf(v3 - m);
                    float sm = e0 + e1 + e2 + e3;
                    sm += __shfl_xor(sm, 1);
                    sm += __shfl_xor(sm, 2);
                    sm += __shfl_xor(sm, 4);
                    sm += __shfl_xor(sm, 8);
                    const float inv = SCALE_S / sm;
                    u16* qp = qsOut + (size_t)(rbase + r) * 1024 + colb;
                    qp[0]  = f2bf(e0 * inv);
                    qp[16] = f2bf(e1 * inv);
                    qp[32] = f2bf(e2 * inv);
                    qp[48] = f2bf(e3 * inv);
                } else {
                    u16* vp = vOut + (size_t)(rbase + r) * 1024 + (colb - 1024);
                    vp[0]  = f2bf(v0);
                    vp[16] = f2bf(v1);
                    vp[32] = f2bf(v2);
                    vp[48] = f2bf(v3);
                }
            }
        }
    }
}

// ---------- ctx partials: Mpart[split][g][d][e] = sum_n exp(qs[n,d]) * v[n,e] ----------
// grid (64 heads, 16 splits), 256 threads; 256 rows per block, chunks of 8 via LDS.
__global__ __launch_bounds__(256) void ctx_accum(
    const u16* __restrict__ qs, const u16* __restrict__ vb,
    float* __restrict__ Mpart, float* __restrict__ Zpart)
{
    __shared__ __align__(16) float ldsE[8][64];
    __shared__ __align__(16) float ldsV[8][64];
    const int t = threadIdx.x;
    const int g = blockIdx.x;          // 0..63  (b = g>>4, h = g&15)
    const int split = blockIdx.y;      // 0..15
    const int b = g >> 4, h = g & 15;
    const int d = t & 63;
    const int e0 = (t >> 6) * 16;
    const size_t rowbase = ((size_t)b * 4096 + (size_t)split * 256) * 1024 + h * 64;

    float acc[16] = {};
    float zacc = 0.f;

    for (int chunk = 0; chunk < 256; chunk += 8) {
#pragma unroll
        for (int c = 0; c < 2; ++c) {
            const int ii = c * 256 + t;         // 0..511
            const int r = ii >> 6, dd = ii & 63;
            const size_t gidx = rowbase + (size_t)(chunk + r) * 1024 + dd;
            ldsE[r][dd] = __expf(bf2f(qs[gidx]));
            ldsV[r][dd] = bf2f(vb[gidx]);
        }
        __syncthreads();
#pragma unroll
        for (int r = 0; r < 8; ++r) {
            const float ev = ldsE[r][d];
            zacc += ev;
            const float4* vp = (const float4*)&ldsV[r][e0];   // wave-uniform -> broadcast
            float4 va = vp[0], vb4 = vp[1], vc4 = vp[2], vd4 = vp[3];
            acc[0]  += ev * va.x;  acc[1]  += ev * va.y;  acc[2]  += ev * va.z;  acc[3]  += ev * va.w;
            acc[4]  += ev * vb4.x; acc[5]  += ev * vb4.y; acc[6]  += ev * vb4.z; acc[7]  += ev * vb4.w;
            acc[8]  += ev * vc4.x; acc[9]  += ev * vc4.y; acc[10] += ev * vc4.z; acc[11] += ev * vc4.w;
            acc[12] += ev * vd4.x; acc[13] += ev * vd4.y; acc[14] += ev * vd4.z; acc[15] += ev * vd4.w;
        }
        __syncthreads();
    }

    float* mp = Mpart + ((size_t)split * 64 + g) * 4096 + (size_t)d * 64 + e0;
#pragma unroll
    for (int i = 0; i < 16; ++i) mp[i] = acc[i];
    if (t < 64) Zpart[((size_t)split * 64 + g) * 64 + d] = zacc;
}

// ---------- reduce partials + normalize: ctx2[g][d][e] = s * sum M / sum Z ----------
__global__ __launch_bounds__(256) void ctx_norm(const float* __restrict__ Mpart,
                                                const float* __restrict__ Zpart,
                                                float* __restrict__ ctx2) {
    const int g = blockIdx.x, t = threadIdx.x;
    __shared__ float rz[64];
    if (t < 64) {
        float zsum = 0.f;
#pragma unroll
        for (int s = 0; s < 16; ++s) zsum += Zpart[((size_t)s * 64 + g) * 64 + t];
        rz[t] = SCALE_S / zsum;
    }
    __syncthreads();
    for (int idx = t; idx < 4096; idx += 256) {
        float m = 0.f;
#pragma unroll
        for (int s = 0; s < 16; ++s) m += Mpart[((size_t)s * 64 + g) * 4096 + idx];
        ctx2[(size_t)g * 4096 + idx] = m * rz[idx >> 6];
    }
}

// ---------- W'T_b[j][h*64+d] = sum_e WoT[j][h*64+e] * ctx2[b,h][d][e] ----------
__global__ __launch_bounds__(256) void woprime(const float* __restrict__ ctx2,
                                               const u16* __restrict__ WoT,
                                               u16* __restrict__ WopT) {
    __shared__ float ctxT[64 * 65];          // [e][d], padded
    __shared__ __align__(16) u16 wo[64 * 64];
    const int t = threadIdx.x;
    const int jt = blockIdx.x, h = blockIdx.y, b = blockIdx.z;
    const int g = b * 16 + h;
    for (int idx = t; idx < 4096; idx += 256) {
        const int d = idx >> 6, e = idx & 63;
        ctxT[e * 65 + d] = ctx2[(size_t)g * 4096 + idx];
    }
    const int j0 = jt * 64;
#pragma unroll
    for (int c = 0; c < 2; ++c) {
        const int ii = c * 256 + t;          // 0..511, 8 bf16 each
        const int j = ii >> 3, c8 = ii & 7;
        *(us8*)&wo[j * 64 + c8 * 8] = *(const us8*)&WoT[(size_t)(j0 + j) * 1024 + h * 64 + c8 * 8];
    }
    __syncthreads();
    const int d = t & 63, w = t >> 6;
    for (int jj = 0; jj < 16; ++jj) {
        const int j = jj * 4 + w;
        float a = 0.f;
#pragma unroll 8
        for (int e = 0; e < 64; ++e) a += bf2f(wo[j * 64 + e]) * ctxT[e * 65 + d];
        WopT[(size_t)b * 1048576 + (size_t)(j0 + j) * 1024 + h * 64 + d] = f2bf(a);
    }
}

// ---------- launch ----------
extern "C" void kernel_launch(void* const* d_in, const int* in_sizes, int n_in,
                              void* d_out, int out_size, void* d_ws, size_t ws_size,
                              hipStream_t stream)
{
    const float* x  = (const float*)d_in[0];
    const float* Wq = (const float*)d_in[1];
    const float* bq = (const float*)d_in[2];
    // d_in[3]=Wk, d_in[4]=bk : dead code in the reference, skipped
    const float* Wv = (const float*)d_in[5];
    const float* bv = (const float*)d_in[6];
    const float* Wo = (const float*)d_in[7];
    const float* bo = (const float*)d_in[8];
    float* out = (float*)d_out;

    char* ws = (char*)d_ws;
    size_t o = 0;
    auto alloc = [&](size_t bytes) { char* p = ws + o; o = (o + bytes + 255) & ~(size_t)255; return p; };
    u16*   x_bf  = (u16*)  alloc(16384ull * 1024 * 2);   // 32 MB
    u16*   WqvT  = (u16*)  alloc(2048ull * 1024 * 2);    //  4 MB  [Wq^T ; Wv^T]
    u16*   WoT   = (u16*)  alloc(1024ull * 1024 * 2);    //  2 MB
    float* bqv   = (float*)alloc(2048ull * 4);
    u16*   qs    = (u16*)  alloc(16384ull * 1024 * 2);   // 32 MB  s*softmax(q)
    u16*   vbuf  = (u16*)  alloc(16384ull * 1024 * 2);   // 32 MB
    float* Mpart = (float*)alloc(16ull * 64 * 4096 * 4); // 16 MB
    float* Zpart = (float*)alloc(16ull * 64 * 64 * 4);
    float* ctx2  = (float*)alloc(64ull * 4096 * 4);      //  1 MB
    u16*   WopT  = (u16*)  alloc(4ull * 1024 * 1024 * 2);//  8 MB
    (void)ws_size; (void)in_sizes; (void)n_in; (void)out_size;

    convert_f32_bf16<<<8192, 256, 0, stream>>>(x, x_bf);
    transpose_convert<<<dim3(32, 32), dim3(32, 8), 0, stream>>>(Wq, WqvT);
    transpose_convert<<<dim3(32, 32), dim3(32, 8), 0, stream>>>(Wv, WqvT + 1024 * 1024);
    transpose_convert<<<dim3(32, 32), dim3(32, 8), 0, stream>>>(Wo, WoT);
    concat_bias<<<8, 256, 0, stream>>>(bq, bv, bqv);

    // QV projection + fused first softmax epilogue
    gemm_bt<<<dim3(128, 16, 1), 256, 0, stream>>>(x_bf, WqvT, bqv, nullptr, qs, vbuf,
                                                  2048, 1024, 1, 0, 0, 0);
    // second softmax (over seq) folded into weighted-sum partials
    ctx_accum<<<dim3(64, 16), 256, 0, stream>>>(qs, vbuf, Mpart, Zpart);
    ctx_norm<<<64, 256, 0, stream>>>(Mpart, Zpart, ctx2);
    // W'_b = blockdiag(ctx2_b) @ Wo  (collapses attn@ctx and @Wo into one GEMM)
    woprime<<<dim3(16, 16, 4), 256, 0, stream>>>(ctx2, WoT, WopT);
    // out = qs @ W'_b + bo   (batched over b via blockIdx.z)
    gemm_bt<<<dim3(32, 8, 4), 256, 0, stream>>>(qs, WopT, bo, out, nullptr, nullptr,
                                                1024, 1024, 0,
                                                4096ll * 1024, 1024ll * 1024, 4096ll * 1024);
}

// Round 2
// 360.730 us; speedup vs baseline: 1.1027x; 1.1027x over previous
//
#include <hip/hip_runtime.h>

typedef unsigned short u16;
typedef __attribute__((ext_vector_type(8))) short short8;   // 8 bf16 (4 VGPRs) - MFMA A/B frag
typedef __attribute__((ext_vector_type(4))) float f4;       // MFMA C/D frag
typedef __attribute__((ext_vector_type(8))) unsigned short us8;

// ---------- helpers ----------
__device__ __forceinline__ u16 f2bf(float f) {              // RNE fp32 -> bf16
    unsigned u = __float_as_uint(f);
    u += 0x7FFFu + ((u >> 16) & 1u);
    return (u16)(u >> 16);
}
__device__ __forceinline__ float bf2f(u16 h) {
    return __uint_as_float(((unsigned)h) << 16);
}

#define GLD16(gp, lp) __builtin_amdgcn_global_load_lds( \
    (const __attribute__((address_space(1))) void*)(gp), \
    (__attribute__((address_space(3))) void*)(lp), 16, 0, 0)

// s = (d_head^0.5)^(-0.25) = 8^(-0.25)
#define SCALE_S 0.594603557501360533f

// ---------- fp32 -> bf16 (8 elems/thread) ----------
__global__ __launch_bounds__(256) void convert_f32_bf16(const float* __restrict__ in,
                                                        u16* __restrict__ out) {
    const size_t i = (size_t)blockIdx.x * 256 + threadIdx.x;
    const float4* p = (const float4*)in + i * 2;
    float4 a = p[0], b = p[1];
    us8 r;
    r[0] = f2bf(a.x); r[1] = f2bf(a.y); r[2] = f2bf(a.z); r[3] = f2bf(a.w);
    r[4] = f2bf(b.x); r[5] = f2bf(b.y); r[6] = f2bf(b.z); r[7] = f2bf(b.w);
    *(us8*)(out + i * 8) = r;
}

// ---------- transpose + convert x3: out[n][k] = bf16(W[k][n]), 1024x1024 ----------
__global__ __launch_bounds__(256) void transpose_convert3(
    const float* __restrict__ Wq, const float* __restrict__ Wv, const float* __restrict__ Wo,
    u16* __restrict__ WqvT, u16* __restrict__ WoT) {
    const float* W; u16* out;
    if (blockIdx.z == 0)      { W = Wq; out = WqvT; }
    else if (blockIdx.z == 1) { W = Wv; out = WqvT + 1024 * 1024; }
    else                      { W = Wo; out = WoT; }
    __shared__ float tile[32][33];
    const int tx = threadIdx.x, ty = threadIdx.y;   // 32 x 8
    const int x = blockIdx.x * 32 + tx;
#pragma unroll
    for (int i = 0; i < 4; ++i) {
        const int y = blockIdx.y * 32 + ty + i * 8;
        tile[ty + i * 8][tx] = W[(size_t)y * 1024 + x];
    }
    __syncthreads();
#pragma unroll
    for (int i = 0; i < 4; ++i) {
        const int yo = blockIdx.x * 32 + ty + i * 8;  // out row (= W col)
        const int xo = blockIdx.y * 32 + tx;          // out col (= W row)
        out[(size_t)yo * 1024 + xo] = f2bf(tile[tx][ty + i * 8]);
    }
}

__global__ void concat_bias(const float* __restrict__ bq, const float* __restrict__ bv,
                            float* __restrict__ bqv) {
    const int i = blockIdx.x * 256 + threadIdx.x;   // 0..2047
    bqv[i] = (i < 1024) ? bq[i] : bv[i - 1024];
}

// ---------- MFMA GEMM: C = A[M,K] * BT[N,K]^T + bias ----------
// LDS tiles are XOR-swizzled: physical 16B-block = logical-block ^ (row & 7).
// Staging keeps the HW-forced base+lane*16 LDS order; the *global* column each
// lane fetches carries the swizzle (same 128B segment -> coalescing unchanged).
// Fragment ds_read_b128: per quarter-wave, 8 distinct blocks x 2 lanes = conflict-free.
// mode 0: fp32 store (final output).  mode 1: fused QV epilogue -- cols < N/2:
// row-softmax over 64-wide head chunk * s -> qsOut (bf16); cols >= N/2: v -> vOut (bf16).
__global__ __launch_bounds__(256) void gemm_bt(
    const u16* __restrict__ A, const u16* __restrict__ BT,
    const float* __restrict__ bias, float* __restrict__ C,
    u16* __restrict__ qsOut, u16* __restrict__ vOut,
    int N, int K, int mode,
    long long Ab, long long Bb, long long Cb)
{
    __shared__ u16 As[128 * 64];
    __shared__ u16 Bs[128 * 64];
    const int t = threadIdx.x;
    const int w = t >> 6, l = t & 63;
    const int quad = l >> 4, lrow = l & 15;
    const int z = blockIdx.z;
    A  += (size_t)z * Ab;
    BT += (size_t)z * Bb;

    // XCD-grouped remap: id%8 = XCD (RR dispatch heuristic) -> give each XCD a
    // contiguous M-range so its A slice is L2-resident. Bijective for nbx%8==0.
    const int nbx = gridDim.x;
    int bx = blockIdx.x, by = blockIdx.y;
    if ((nbx & 7) == 0) {
        const int id = blockIdx.x + nbx * blockIdx.y;
        const int xcd = id & 7, j = id >> 3;
        const int xs = nbx >> 3;
        bx = xcd * xs + (j % xs);
        by = j / xs;
    }
    const int m0 = bx * 128;
    const int n0 = by * 128;
    const int wm = (w & 1) * 64, wn = (w >> 1) * 64;

    const int srow = t >> 3;                              // staging row within 32-row pass
    const int scol_l = (t & 7) * 8;                       // LDS col (HW-forced lane order)
    const int scol_g = ((t & 7) ^ (srow & 7)) * 8;        // swizzled global col

    f4 acc[4][4] = {};

    for (int k0 = 0; k0 < K; k0 += 64) {
#pragma unroll
        for (int p = 0; p < 4; ++p) {
            const int row = p * 32 + srow;
            GLD16(A  + (size_t)(m0 + row) * K + k0 + scol_g, &As[row * 64 + scol_l]);
            GLD16(BT + (size_t)(n0 + row) * K + k0 + scol_g, &Bs[row * 64 + scol_l]);
        }
        __syncthreads();
        // phys elem offset for logical block (kk*4+quad) at row with row&7==lrow&7:
        const int swz = (quad ^ (lrow & 7)) << 3;
#pragma unroll
        for (int kk = 0; kk < 2; ++kk) {
            const int koff = swz ^ (kk << 5);
            short8 a[4], b[4];
#pragma unroll
            for (int i = 0; i < 4; ++i)
                a[i] = *(const short8*)&As[(wm + i * 16 + lrow) * 64 + koff];
#pragma unroll
            for (int j = 0; j < 4; ++j)
                b[j] = *(const short8*)&Bs[(wn + j * 16 + lrow) * 64 + koff];
#pragma unroll
            for (int i = 0; i < 4; ++i)
#pragma unroll
                for (int j = 0; j < 4; ++j)
                    acc[i][j] = __builtin_amdgcn_mfma_f32_16x16x32_bf16(a[i], b[j], acc[i][j], 0, 0, 0);
        }
        __syncthreads();
    }

    const int colb = n0 + wn + lrow;
    const float b0 = bias[colb], b1 = bias[colb + 16], b2 = bias[colb + 32], b3 = bias[colb + 48];

    if (mode == 0) {
        C += (size_t)z * Cb;
#pragma unroll
        for (int i = 0; i < 4; ++i) {
            const int rbase = m0 + wm + i * 16 + quad * 4;
#pragma unroll
            for (int r = 0; r < 4; ++r) {
                float* cp = C + (size_t)(rbase + r) * N + colb;
                cp[0]  = acc[i][0][r] + b0;
                cp[16] = acc[i][1][r] + b1;
                cp[32] = acc[i][2][r] + b2;
                cp[48] = acc[i][3][r] + b3;
            }
        }
    } else {
        const bool isQ = (n0 + wn) < (N >> 1);   // wave-uniform
#pragma unroll
        for (int i = 0; i < 4; ++i) {
            const int rbase = m0 + wm + i * 16 + quad * 4;
#pragma unroll
            for (int r = 0; r < 4; ++r) {
                float v0 = acc[i][0][r] + b0;
                float v1 = acc[i][1][r] + b1;
                float v2 = acc[i][2][r] + b2;
                float v3 = acc[i][3][r] + b3;
                if (isQ) {
                    // softmax over this row's 64-wide head chunk (16 lanes x 4 frags)
                    float m = fmaxf(fmaxf(v0, v1), fmaxf(v2, v3));
                    m = fmaxf(m, __shfl_xor(m, 1));
                    m = fmaxf(m, __shfl_xor(m, 2));
                    m = fmaxf(m, __shfl_xor(m, 4));
                    m = fmaxf(m, __shfl_xor(m, 8));
                    float e0 = __expf(v0 - m), e1 = __expf(v1 - m);
                    float e2 = __expf(v2 - m), e3 = __expf(v3 - m);
                    float sm = e0 + e1 + e2 + e3;
                    sm += __shfl_xor(sm, 1);
                    sm += __shfl_xor(sm, 2);
                    sm += __shfl_xor(sm, 4);
                    sm += __shfl_xor(sm, 8);
                    const float inv = SCALE_S / sm;
                    u16* qp = qsOut + (size_t)(rbase + r) * 1024 + colb;
                    qp[0]  = f2bf(e0 * inv);
                    qp[16] = f2bf(e1 * inv);
                    qp[32] = f2bf(e2 * inv);
                    qp[48] = f2bf(e3 * inv);
                } else {
                    u16* vp = vOut + (size_t)(rbase + r) * 1024 + (colb - 1024);
                    vp[0]  = f2bf(v0);
                    vp[16] = f2bf(v1);
                    vp[32] = f2bf(v2);
                    vp[48] = f2bf(v3);
                }
            }
        }
    }
}

// ---------- ctx partials: Mpart[split][g][d][e] = sum_n exp(qs[n,d]) * v[n,e] ----------
// grid (64 heads, 16 splits), 256 threads; 256 rows/block in 32-row chunks.
// us8 (16B/lane) global loads; fp32 staging in LDS stride-68 (conflict-free b128).
#define ZSTR 68
__global__ __launch_bounds__(256) void ctx_accum(
    const u16* __restrict__ qs, const u16* __restrict__ vb,
    float* __restrict__ Mpart, float* __restrict__ Zpart)
{
    __shared__ float ldsE[32][ZSTR];
    __shared__ float ldsV[32][ZSTR];
    const int t = threadIdx.x;
    const int g = blockIdx.x;          // 0..63  (b = g>>4, h = g&15)
    const int split = blockIdx.y;      // 0..15
    const int b = g >> 4, h = g & 15;
    const int d = t & 63;
    const int e0 = (t >> 6) * 16;
    const int r = t >> 3, cb = t & 7;  // staging: row 0..31, 8-col block
    const size_t rowbase = ((size_t)b * 4096 + (size_t)split * 256) * 1024 + h * 64;

    float acc[16] = {};
    float z8[8] = {};

    for (int chunk = 0; chunk < 256; chunk += 32) {
        const size_t gi = rowbase + (size_t)(chunk + r) * 1024 + cb * 8;
        us8 q8 = *(const us8*)(qs + gi);
        us8 v8 = *(const us8*)(vb + gi);
        float e[8], vv[8];
#pragma unroll
        for (int j2 = 0; j2 < 8; ++j2) {
            e[j2] = __expf(bf2f((u16)q8[j2]));
            z8[j2] += e[j2];
            vv[j2] = bf2f((u16)v8[j2]);
        }
        __syncthreads();               // protect previous chunk's reads
        *(float4*)&ldsE[r][cb * 8]     = *(float4*)&e[0];
        *(float4*)&ldsE[r][cb * 8 + 4] = *(float4*)&e[4];
        *(float4*)&ldsV[r][cb * 8]     = *(float4*)&vv[0];
        *(float4*)&ldsV[r][cb * 8 + 4] = *(float4*)&vv[4];
        __syncthreads();
#pragma unroll 8
        for (int rr = 0; rr < 32; ++rr) {
            const float ev = ldsE[rr][d];
            const float4* vp = (const float4*)&ldsV[rr][e0];   // wave-uniform -> broadcast
            float4 va = vp[0], vb4 = vp[1], vc4 = vp[2], vd4 = vp[3];
            acc[0]  += ev * va.x;  acc[1]  += ev * va.y;  acc[2]  += ev * va.z;  acc[3]  += ev * va.w;
            acc[4]  += ev * vb4.x; acc[5]  += ev * vb4.y; acc[6]  += ev * vb4.z; acc[7]  += ev * vb4.w;
            acc[8]  += ev * vc4.x; acc[9]  += ev * vc4.y; acc[10] += ev * vc4.z; acc[11] += ev * vc4.w;
            acc[12] += ev * vd4.x; acc[13] += ev * vd4.y; acc[14] += ev * vd4.z; acc[15] += ev * vd4.w;
        }
    }

    // Z reduction: reuse ldsE
    __syncthreads();
    *(float4*)&ldsE[r][cb * 8]     = *(float4*)&z8[0];
    *(float4*)&ldsE[r][cb * 8 + 4] = *(float4*)&z8[4];
    __syncthreads();
    if (t < 64) {
        float zs = 0.f;
#pragma unroll
        for (int rr = 0; rr < 32; ++rr) zs += ldsE[rr][t];
        Zpart[((size_t)split * 64 + g) * 64 + t] = zs;
    }

    float* mp = Mpart + ((size_t)split * 64 + g) * 4096 + (size_t)d * 64 + e0;
    *(float4*)&mp[0]  = *(float4*)&acc[0];
    *(float4*)&mp[4]  = *(float4*)&acc[4];
    *(float4*)&mp[8]  = *(float4*)&acc[8];
    *(float4*)&mp[12] = *(float4*)&acc[12];
}

// ---------- reduce partials + normalize: ctx2[g][d][e] = s * sum M / sum Z ----------
__global__ __launch_bounds__(256) void ctx_norm(const float* __restrict__ Mpart,
                                                const float* __restrict__ Zpart,
                                                float* __restrict__ ctx2) {
    const int g = blockIdx.x, t = threadIdx.x;
    __shared__ float rz[64];
    if (t < 64) {
        float zsum = 0.f;
#pragma unroll
        for (int s = 0; s < 16; ++s) zsum += Zpart[((size_t)s * 64 + g) * 64 + t];
        rz[t] = SCALE_S / zsum;
    }
    __syncthreads();
    for (int idx = t; idx < 4096; idx += 256) {
        float m = 0.f;
#pragma unroll
        for (int s = 0; s < 16; ++s) m += Mpart[((size_t)s * 64 + g) * 4096 + idx];
        ctx2[(size_t)g * 4096 + idx] = m * rz[idx >> 6];
    }
}

// ---------- W'T_b[j][h*64+d] = sum_e WoT[j][h*64+e] * ctx2[b,h][d][e] ----------
__global__ __launch_bounds__(256) void woprime(const float* __restrict__ ctx2,
                                               const u16* __restrict__ WoT,
                                               u16* __restrict__ WopT) {
    __shared__ float ctxT[64 * 65];          // [e][d], padded
    __shared__ __align__(16) u16 wo[64 * 64];
    const int t = threadIdx.x;
    const int jt = blockIdx.x, h = blockIdx.y, b = blockIdx.z;
    const int g = b * 16 + h;
    for (int idx = t; idx < 4096; idx += 256) {
        const int d = idx >> 6, e = idx & 63;
        ctxT[e * 65 + d] = ctx2[(size_t)g * 4096 + idx];
    }
    const int j0 = jt * 64;
#pragma unroll
    for (int c = 0; c < 2; ++c) {
        const int ii = c * 256 + t;          // 0..511, 8 bf16 each
        const int j = ii >> 3, c8 = ii & 7;
        *(us8*)&wo[j * 64 + c8 * 8] = *(const us8*)&WoT[(size_t)(j0 + j) * 1024 + h * 64 + c8 * 8];
    }
    __syncthreads();
    const int d = t & 63, w = t >> 6;
    for (int jj = 0; jj < 16; ++jj) {
        const int j = jj * 4 + w;
        float a = 0.f;
#pragma unroll 8
        for (int e = 0; e < 64; ++e) a += bf2f(wo[j * 64 + e]) * ctxT[e * 65 + d];
        WopT[(size_t)b * 1048576 + (size_t)(j0 + j) * 1024 + h * 64 + d] = f2bf(a);
    }
}

// ---------- launch ----------
extern "C" void kernel_launch(void* const* d_in, const int* in_sizes, int n_in,
                              void* d_out, int out_size, void* d_ws, size_t ws_size,
                              hipStream_t stream)
{
    const float* x  = (const float*)d_in[0];
    const float* Wq = (const float*)d_in[1];
    const float* bq = (const float*)d_in[2];
    // d_in[3]=Wk, d_in[4]=bk : dead code in the reference, skipped
    const float* Wv = (const float*)d_in[5];
    const float* bv = (const float*)d_in[6];
    const float* Wo = (const float*)d_in[7];
    const float* bo = (const float*)d_in[8];
    float* out = (float*)d_out;

    char* ws = (char*)d_ws;
    size_t o = 0;
    auto alloc = [&](size_t bytes) { char* p = ws + o; o = (o + bytes + 255) & ~(size_t)255; return p; };
    u16*   x_bf  = (u16*)  alloc(16384ull * 1024 * 2);   // 32 MB
    u16*   WqvT  = (u16*)  alloc(2048ull * 1024 * 2);    //  4 MB  [Wq^T ; Wv^T]
    u16*   WoT   = (u16*)  alloc(1024ull * 1024 * 2);    //  2 MB
    float* bqv   = (float*)alloc(2048ull * 4);
    u16*   qs    = (u16*)  alloc(16384ull * 1024 * 2);   // 32 MB  s*softmax(q)
    u16*   vbuf  = (u16*)  alloc(16384ull * 1024 * 2);   // 32 MB
    float* Mpart = (float*)alloc(16ull * 64 * 4096 * 4); // 16 MB
    float* Zpart = (float*)alloc(16ull * 64 * 64 * 4);
    float* ctx2  = (float*)alloc(64ull * 4096 * 4);      //  1 MB
    u16*   WopT  = (u16*)  alloc(4ull * 1024 * 1024 * 2);//  8 MB
    (void)ws_size; (void)in_sizes; (void)n_in; (void)out_size;

    convert_f32_bf16<<<8192, 256, 0, stream>>>(x, x_bf);
    transpose_convert3<<<dim3(32, 32, 3), dim3(32, 8), 0, stream>>>(Wq, Wv, Wo, WqvT, WoT);
    concat_bias<<<8, 256, 0, stream>>>(bq, bv, bqv);

    // QV projection + fused first softmax epilogue
    gemm_bt<<<dim3(128, 16, 1), 256, 0, stream>>>(x_bf, WqvT, bqv, nullptr, qs, vbuf,
                                                  2048, 1024, 1, 0, 0, 0);
    // second softmax (over seq) folded into weighted-sum partials
    ctx_accum<<<dim3(64, 16), 256, 0, stream>>>(qs, vbuf, Mpart, Zpart);
    ctx_norm<<<64, 256, 0, stream>>>(Mpart, Zpart, ctx2);
    // W'_b = blockdiag(ctx2_b) @ Wo  (collapses attn@ctx and @Wo into one GEMM)
    woprime<<<dim3(16, 16, 4), 256, 0, stream>>>(ctx2, WoT, WopT);
    // out = qs @ W'_b + bo   (batched over b via blockIdx.z)
    gemm_bt<<<dim3(32, 8, 4), 256, 0, stream>>>(qs, WopT, bo, out, nullptr, nullptr,
                                                1024, 1024, 0,
                                                4096ll * 1024, 1024ll * 1024, 4096ll * 1024);
}

// Round 3
// 360.424 us; speedup vs baseline: 1.1036x; 1.0008x over previous
//
#include <hip/hip_runtime.h>

typedef unsigned short u16;
typedef __attribute__((ext_vector_type(8))) short short8;   // 8 bf16 (4 VGPRs) - MFMA A/B frag
typedef __attribute__((ext_vector_type(4))) float f4;       // MFMA C/D frag
typedef __attribute__((ext_vector_type(8))) unsigned short us8;

// ---------- helpers ----------
__device__ __forceinline__ u16 f2bf(float f) {              // RNE fp32 -> bf16
    unsigned u = __float_as_uint(f);
    u += 0x7FFFu + ((u >> 16) & 1u);
    return (u16)(u >> 16);
}
__device__ __forceinline__ float bf2f(u16 h) {
    return __uint_as_float(((unsigned)h) << 16);
}

#define GLD16(gp, lp) __builtin_amdgcn_global_load_lds( \
    (const __attribute__((address_space(1))) void*)(gp), \
    (__attribute__((address_space(3))) void*)(lp), 16, 0, 0)

// s = (d_head^0.5)^(-0.25) = 8^(-0.25)
#define SCALE_S 0.594603557501360533f

// ---------- fp32 -> bf16 (8 elems/thread) ----------
__global__ __launch_bounds__(256) void convert_f32_bf16(const float* __restrict__ in,
                                                        u16* __restrict__ out) {
    const size_t i = (size_t)blockIdx.x * 256 + threadIdx.x;
    const float4* p = (const float4*)in + i * 2;
    float4 a = p[0], b = p[1];
    us8 r;
    r[0] = f2bf(a.x); r[1] = f2bf(a.y); r[2] = f2bf(a.z); r[3] = f2bf(a.w);
    r[4] = f2bf(b.x); r[5] = f2bf(b.y); r[6] = f2bf(b.z); r[7] = f2bf(b.w);
    *(us8*)(out + i * 8) = r;
}

// ---------- transpose + convert x3: out[n][k] = bf16(W[k][n]), 1024x1024 ----------
__global__ __launch_bounds__(256) void transpose_convert3(
    const float* __restrict__ Wq, const float* __restrict__ Wv, const float* __restrict__ Wo,
    u16* __restrict__ WqvT, u16* __restrict__ WoT) {
    const float* W; u16* out;
    if (blockIdx.z == 0)      { W = Wq; out = WqvT; }
    else if (blockIdx.z == 1) { W = Wv; out = WqvT + 1024 * 1024; }
    else                      { W = Wo; out = WoT; }
    __shared__ float tile[32][33];
    const int tx = threadIdx.x, ty = threadIdx.y;   // 32 x 8
    const int x = blockIdx.x * 32 + tx;
#pragma unroll
    for (int i = 0; i < 4; ++i) {
        const int y = blockIdx.y * 32 + ty + i * 8;
        tile[ty + i * 8][tx] = W[(size_t)y * 1024 + x];
    }
    __syncthreads();
#pragma unroll
    for (int i = 0; i < 4; ++i) {
        const int yo = blockIdx.x * 32 + ty + i * 8;  // out row (= W col)
        const int xo = blockIdx.y * 32 + tx;          // out col (= W row)
        out[(size_t)yo * 1024 + xo] = f2bf(tile[tx][ty + i * 8]);
    }
}

__global__ void concat_bias(const float* __restrict__ bq, const float* __restrict__ bv,
                            float* __restrict__ bqv) {
    const int i = blockIdx.x * 256 + threadIdx.x;   // 0..2047
    bqv[i] = (i < 1024) ? bq[i] : bv[i - 1024];
}

// ---------- MFMA GEMM: C = A[M,K] * BT[N,K]^T + bias ----------
// LDS tiles XOR-swizzled (conflict-free frag reads, verified R2: SQ_LDS_BANK_CONFLICT=0).
// Staging pointers hoisted out of the K-loop and advanced by += 64 (cuts the
// v_lshl_add_u64 address rebuilds that made VALUBusy=43% in R2).
// mode 0: fp32 store.  mode 1: fused QV epilogue (row-softmax*s -> qsOut | v -> vOut).
__global__ __launch_bounds__(256) void gemm_bt(
    const u16* __restrict__ A, const u16* __restrict__ BT,
    const float* __restrict__ bias, float* __restrict__ C,
    u16* __restrict__ qsOut, u16* __restrict__ vOut,
    int N, int K, int mode,
    long long Ab, long long Bb, long long Cb)
{
    __shared__ u16 As[128 * 64];
    __shared__ u16 Bs[128 * 64];
    const int t = threadIdx.x;
    const int w = t >> 6, l = t & 63;
    const int quad = l >> 4, lrow = l & 15;
    const int z = blockIdx.z;
    A  += (size_t)z * Ab;
    BT += (size_t)z * Bb;

    // XCD-grouped remap: id%8 = XCD -> contiguous M-range per XCD (L2-resident A).
    const int nbx = gridDim.x;
    int bx = blockIdx.x, by = blockIdx.y;
    if ((nbx & 7) == 0) {
        const int id = blockIdx.x + nbx * blockIdx.y;
        const int xcd = id & 7, j = id >> 3;
        const int xs = nbx >> 3;
        bx = xcd * xs + (j % xs);
        by = j / xs;
    }
    const int m0 = bx * 128;
    const int n0 = by * 128;
    const int wm = (w & 1) * 64, wn = (w >> 1) * 64;

    const int srow = t >> 3;                              // staging row within 32-row pass
    const int scol_l = (t & 7) * 8;                       // LDS col (HW-forced lane order)
    const int scol_g = ((t & 7) ^ (srow & 7)) * 8;        // swizzled global col

    // hoisted staging pointers (8 streams), advanced by 64 elems per K-iter
    const u16* ap[4];
    const u16* bp[4];
    u16* al[4];
    u16* bl[4];
#pragma unroll
    for (int p = 0; p < 4; ++p) {
        ap[p] = A  + (size_t)(m0 + p * 32 + srow) * K + scol_g;
        bp[p] = BT + (size_t)(n0 + p * 32 + srow) * K + scol_g;
        al[p] = &As[(p * 32 + srow) * 64 + scol_l];
        bl[p] = &Bs[(p * 32 + srow) * 64 + scol_l];
    }

    f4 acc[4][4] = {};
    const int swz = (quad ^ (lrow & 7)) << 3;

    for (int it = K >> 6; it > 0; --it) {
#pragma unroll
        for (int p = 0; p < 4; ++p) {
            GLD16(ap[p], al[p]);
            GLD16(bp[p], bl[p]);
            ap[p] += 64; bp[p] += 64;
        }
        __syncthreads();
#pragma unroll
        for (int kk = 0; kk < 2; ++kk) {
            const int koff = swz ^ (kk << 5);
            short8 a[4], b[4];
#pragma unroll
            for (int i = 0; i < 4; ++i)
                a[i] = *(const short8*)&As[(wm + i * 16 + lrow) * 64 + koff];
#pragma unroll
            for (int j = 0; j < 4; ++j)
                b[j] = *(const short8*)&Bs[(wn + j * 16 + lrow) * 64 + koff];
#pragma unroll
            for (int i = 0; i < 4; ++i)
#pragma unroll
                for (int j = 0; j < 4; ++j)
                    acc[i][j] = __builtin_amdgcn_mfma_f32_16x16x32_bf16(a[i], b[j], acc[i][j], 0, 0, 0);
        }
        __syncthreads();
    }

    const int colb = n0 + wn + lrow;
    const float b0 = bias[colb], b1 = bias[colb + 16], b2 = bias[colb + 32], b3 = bias[colb + 48];

    if (mode == 0) {
        C += (size_t)z * Cb;
#pragma unroll
        for (int i = 0; i < 4; ++i) {
            const int rbase = m0 + wm + i * 16 + quad * 4;
#pragma unroll
            for (int r = 0; r < 4; ++r) {
                float* cp = C + (size_t)(rbase + r) * N + colb;
                cp[0]  = acc[i][0][r] + b0;
                cp[16] = acc[i][1][r] + b1;
                cp[32] = acc[i][2][r] + b2;
                cp[48] = acc[i][3][r] + b3;
            }
        }
    } else {
        const bool isQ = (n0 + wn) < (N >> 1);   // wave-uniform
#pragma unroll
        for (int i = 0; i < 4; ++i) {
            const int rbase = m0 + wm + i * 16 + quad * 4;
#pragma unroll
            for (int r = 0; r < 4; ++r) {
                float v0 = acc[i][0][r] + b0;
                float v1 = acc[i][1][r] + b1;
                float v2 = acc[i][2][r] + b2;
                float v3 = acc[i][3][r] + b3;
                if (isQ) {
                    float m = fmaxf(fmaxf(v0, v1), fmaxf(v2, v3));
                    m = fmaxf(m, __shfl_xor(m, 1));
                    m = fmaxf(m, __shfl_xor(m, 2));
                    m = fmaxf(m, __shfl_xor(m, 4));
                    m = fmaxf(m, __shfl_xor(m, 8));
                    float e0 = __expf(v0 - m), e1 = __expf(v1 - m);
                    float e2 = __expf(v2 - m), e3 = __expf(v3 - m);
                    float sm = e0 + e1 + e2 + e3;
                    sm += __shfl_xor(sm, 1);
                    sm += __shfl_xor(sm, 2);
                    sm += __shfl_xor(sm, 4);
                    sm += __shfl_xor(sm, 8);
                    const float inv = SCALE_S / sm;
                    u16* qp = qsOut + (size_t)(rbase + r) * 1024 + colb;
                    qp[0]  = f2bf(e0 * inv);
                    qp[16] = f2bf(e1 * inv);
                    qp[32] = f2bf(e2 * inv);
                    qp[48] = f2bf(e3 * inv);
                } else {
                    u16* vp = vOut + (size_t)(rbase + r) * 1024 + (colb - 1024);
                    vp[0]  = f2bf(v0);
                    vp[16] = f2bf(v1);
                    vp[32] = f2bf(v2);
                    vp[48] = f2bf(v3);
                }
            }
        }
    }
}

// ---------- ctx partials: Mpart[split][g][d][e] = sum_n exp(qs[n,d]) * v[n,e] ----------
#define ZSTR 68
__global__ __launch_bounds__(256) void ctx_accum(
    const u16* __restrict__ qs, const u16* __restrict__ vb,
    float* __restrict__ Mpart, float* __restrict__ Zpart)
{
    __shared__ float ldsE[32][ZSTR];
    __shared__ float ldsV[32][ZSTR];
    const int t = threadIdx.x;
    const int g = blockIdx.x;          // 0..63  (b = g>>4, h = g&15)
    const int split = blockIdx.y;      // 0..15
    const int b = g >> 4, h = g & 15;
    const int d = t & 63;
    const int e0 = (t >> 6) * 16;
    const int r = t >> 3, cb = t & 7;  // staging: row 0..31, 8-col block
    const size_t rowbase = ((size_t)b * 4096 + (size_t)split * 256) * 1024 + h * 64;

    float2 acc2[8] = {};               // float2 math -> v_pk_fma_f32
    float z8[8] = {};

    for (int chunk = 0; chunk < 256; chunk += 32) {
        const size_t gi = rowbase + (size_t)(chunk + r) * 1024 + cb * 8;
        us8 q8 = *(const us8*)(qs + gi);
        us8 v8 = *(const us8*)(vb + gi);
        float e[8], vv[8];
#pragma unroll
        for (int j2 = 0; j2 < 8; ++j2) {
            e[j2] = __expf(bf2f((u16)q8[j2]));
            z8[j2] += e[j2];
            vv[j2] = bf2f((u16)v8[j2]);
        }
        __syncthreads();               // protect previous chunk's reads
        *(float4*)&ldsE[r][cb * 8]     = *(float4*)&e[0];
        *(float4*)&ldsE[r][cb * 8 + 4] = *(float4*)&e[4];
        *(float4*)&ldsV[r][cb * 8]     = *(float4*)&vv[0];
        *(float4*)&ldsV[r][cb * 8 + 4] = *(float4*)&vv[4];
        __syncthreads();
#pragma unroll 8
        for (int rr = 0; rr < 32; ++rr) {
            const float ev = ldsE[rr][d];
            const float2* vp2 = (const float2*)&ldsV[rr][e0];   // wave-uniform -> broadcast
#pragma unroll
            for (int q = 0; q < 8; ++q) {
                float2 v2 = vp2[q];
                acc2[q].x += ev * v2.x;
                acc2[q].y += ev * v2.y;
            }
        }
    }

    // Z reduction: reuse ldsE
    __syncthreads();
    *(float4*)&ldsE[r][cb * 8]     = *(float4*)&z8[0];
    *(float4*)&ldsE[r][cb * 8 + 4] = *(float4*)&z8[4];
    __syncthreads();
    if (t < 64) {
        float zs = 0.f;
#pragma unroll
        for (int rr = 0; rr < 32; ++rr) zs += ldsE[rr][t];
        Zpart[((size_t)split * 64 + g) * 64 + t] = zs;
    }

    float* mp = Mpart + ((size_t)split * 64 + g) * 4096 + (size_t)d * 64 + e0;
    const float* af = (const float*)acc2;
    *(float4*)&mp[0]  = *(const float4*)&af[0];
    *(float4*)&mp[4]  = *(const float4*)&af[4];
    *(float4*)&mp[8]  = *(const float4*)&af[8];
    *(float4*)&mp[12] = *(const float4*)&af[12];
}

// ---------- reduce partials + normalize: ctx2[g][d][e] = s * sum M / sum Z ----------
__global__ __launch_bounds__(256) void ctx_norm(const float* __restrict__ Mpart,
                                                const float* __restrict__ Zpart,
                                                float* __restrict__ ctx2) {
    const int g = blockIdx.x, t = threadIdx.x;
    __shared__ float rz[64];
    if (t < 64) {
        float zsum = 0.f;
#pragma unroll
        for (int s = 0; s < 16; ++s) zsum += Zpart[((size_t)s * 64 + g) * 64 + t];
        rz[t] = SCALE_S / zsum;
    }
    __syncthreads();
    for (int idx = t; idx < 4096; idx += 256) {
        float m = 0.f;
#pragma unroll
        for (int s = 0; s < 16; ++s) m += Mpart[((size_t)s * 64 + g) * 4096 + idx];
        ctx2[(size_t)g * 4096 + idx] = m * rz[idx >> 6];
    }
}

// ---------- W'T_b[j][h*64+d] = sum_e WoT[j][h*64+e] * ctx2[b,h][d][e] ----------
// e-blocked: ctxT read once per e-block (was: once per (jj,e) -> 2048 ds-issues),
// wo via wave-uniform us8 broadcasts. VALU-bound at ~2k instrs/thread.
__global__ __launch_bounds__(256) void woprime(const float* __restrict__ ctx2,
                                               const u16* __restrict__ WoT,
                                               u16* __restrict__ WopT) {
    __shared__ float ctxT[64 * 65];          // [e][d], padded
    __shared__ __align__(16) u16 wo[64 * 64];
    const int t = threadIdx.x;
    const int jt = blockIdx.x, h = blockIdx.y, b = blockIdx.z;
    const int g = b * 16 + h;
    for (int idx = t; idx < 4096; idx += 256) {
        const int d = idx >> 6, e = idx & 63;
        ctxT[e * 65 + d] = ctx2[(size_t)g * 4096 + idx];
    }
    const int j0 = jt * 64;
#pragma unroll
    for (int c = 0; c < 2; ++c) {
        const int ii = c * 256 + t;          // 0..511, 8 bf16 each
        const int j = ii >> 3, c8 = ii & 7;
        *(us8*)&wo[j * 64 + c8 * 8] = *(const us8*)&WoT[(size_t)(j0 + j) * 1024 + h * 64 + c8 * 8];
    }
    __syncthreads();
    const int d = t & 63, w = t >> 6;
    float accj[16] = {};
    for (int eb = 0; eb < 8; ++eb) {
        float c8[8];
#pragma unroll
        for (int e = 0; e < 8; ++e) c8[e] = ctxT[(eb * 8 + e) * 65 + d];
#pragma unroll
        for (int jj = 0; jj < 16; ++jj) {
            us8 w8 = *(const us8*)&wo[(jj * 4 + w) * 64 + eb * 8];   // wave-uniform broadcast
#pragma unroll
            for (int e = 0; e < 8; ++e)
                accj[jj] += bf2f((u16)w8[e]) * c8[e];
        }
    }
#pragma unroll
    for (int jj = 0; jj < 16; ++jj)
        WopT[(size_t)b * 1048576 + (size_t)(j0 + jj * 4 + w) * 1024 + h * 64 + d] = f2bf(accj[jj]);
}

// ---------- launch ----------
extern "C" void kernel_launch(void* const* d_in, const int* in_sizes, int n_in,
                              void* d_out, int out_size, void* d_ws, size_t ws_size,
                              hipStream_t stream)
{
    const float* x  = (const float*)d_in[0];
    const float* Wq = (const float*)d_in[1];
    const float* bq = (const float*)d_in[2];
    // d_in[3]=Wk, d_in[4]=bk : dead code in the reference, skipped
    const float* Wv = (const float*)d_in[5];
    const float* bv = (const float*)d_in[6];
    const float* Wo = (const float*)d_in[7];
    const float* bo = (const float*)d_in[8];
    float* out = (float*)d_out;

    char* ws = (char*)d_ws;
    size_t o = 0;
    auto alloc = [&](size_t bytes) { char* p = ws + o; o = (o + bytes + 255) & ~(size_t)255; return p; };
    u16*   x_bf  = (u16*)  alloc(16384ull * 1024 * 2);   // 32 MB
    u16*   WqvT  = (u16*)  alloc(2048ull * 1024 * 2);    //  4 MB  [Wq^T ; Wv^T]
    u16*   WoT   = (u16*)  alloc(1024ull * 1024 * 2);    //  2 MB
    float* bqv   = (float*)alloc(2048ull * 4);
    u16*   qs    = (u16*)  alloc(16384ull * 1024 * 2);   // 32 MB  s*softmax(q)
    u16*   vbuf  = (u16*)  alloc(16384ull * 1024 * 2);   // 32 MB
    float* Mpart = (float*)alloc(16ull * 64 * 4096 * 4); // 16 MB
    float* Zpart = (float*)alloc(16ull * 64 * 64 * 4);
    float* ctx2  = (float*)alloc(64ull * 4096 * 4);      //  1 MB
    u16*   WopT  = (u16*)  alloc(4ull * 1024 * 1024 * 2);//  8 MB
    (void)ws_size; (void)in_sizes; (void)n_in; (void)out_size;

    convert_f32_bf16<<<8192, 256, 0, stream>>>(x, x_bf);
    transpose_convert3<<<dim3(32, 32, 3), dim3(32, 8), 0, stream>>>(Wq, Wv, Wo, WqvT, WoT);
    concat_bias<<<8, 256, 0, stream>>>(bq, bv, bqv);

    // QV projection + fused first softmax epilogue
    gemm_bt<<<dim3(128, 16, 1), 256, 0, stream>>>(x_bf, WqvT, bqv, nullptr, qs, vbuf,
                                                  2048, 1024, 1, 0, 0, 0);
    // second softmax (over seq) folded into weighted-sum partials
    ctx_accum<<<dim3(64, 16), 256, 0, stream>>>(qs, vbuf, Mpart, Zpart);
    ctx_norm<<<64, 256, 0, stream>>>(Mpart, Zpart, ctx2);
    // W'_b = blockdiag(ctx2_b) @ Wo  (collapses attn@ctx and @Wo into one GEMM)
    woprime<<<dim3(16, 16, 4), 256, 0, stream>>>(ctx2, WoT, WopT);
    // out = qs @ W'_b + bo   (batched over b via blockIdx.z)
    gemm_bt<<<dim3(32, 8, 4), 256, 0, stream>>>(qs, WopT, bo, out, nullptr, nullptr,
                                                1024, 1024, 0,
                                                4096ll * 1024, 1024ll * 1024, 4096ll * 1024);
}

// Round 4
// 326.306 us; speedup vs baseline: 1.2190x; 1.1046x over previous
//
#include <hip/hip_runtime.h>

typedef unsigned short u16;
typedef __attribute__((ext_vector_type(8))) short short8;   // 8 bf16 (4 VGPRs) - MFMA A/B frag
typedef __attribute__((ext_vector_type(4))) float f4;       // MFMA C/D frag
typedef __attribute__((ext_vector_type(8))) unsigned short us8;

// ---------- helpers ----------
__device__ __forceinline__ u16 f2bf(float f) {              // RNE fp32 -> bf16
    unsigned u = __float_as_uint(f);
    u += 0x7FFFu + ((u >> 16) & 1u);
    return (u16)(u >> 16);
}
__device__ __forceinline__ float bf2f(u16 h) {
    return __uint_as_float(((unsigned)h) << 16);
}

#define GLD16(gp, lp) __builtin_amdgcn_global_load_lds( \
    (const __attribute__((address_space(1))) void*)(gp), \
    (__attribute__((address_space(3))) void*)(lp), 16, 0, 0)

// s = (d_head^0.5)^(-0.25) = 8^(-0.25)
#define SCALE_S 0.594603557501360533f

// ---------- fp32 -> bf16 (8 elems/thread) ----------
__global__ __launch_bounds__(256) void convert_f32_bf16(const float* __restrict__ in,
                                                        u16* __restrict__ out) {
    const size_t i = (size_t)blockIdx.x * 256 + threadIdx.x;
    const float4* p = (const float4*)in + i * 2;
    float4 a = p[0], b = p[1];
    us8 r;
    r[0] = f2bf(a.x); r[1] = f2bf(a.y); r[2] = f2bf(a.z); r[3] = f2bf(a.w);
    r[4] = f2bf(b.x); r[5] = f2bf(b.y); r[6] = f2bf(b.z); r[7] = f2bf(b.w);
    *(us8*)(out + i * 8) = r;
}

// ---------- transpose + convert x3: out[n][k] = bf16(W[k][n]), 1024x1024 ----------
__global__ __launch_bounds__(256) void transpose_convert3(
    const float* __restrict__ Wq, const float* __restrict__ Wv, const float* __restrict__ Wo,
    u16* __restrict__ WqvT, u16* __restrict__ WoT) {
    const float* W; u16* out;
    if (blockIdx.z == 0)      { W = Wq; out = WqvT; }
    else if (blockIdx.z == 1) { W = Wv; out = WqvT + 1024 * 1024; }
    else                      { W = Wo; out = WoT; }
    __shared__ float tile[32][33];
    const int tx = threadIdx.x, ty = threadIdx.y;   // 32 x 8
    const int x = blockIdx.x * 32 + tx;
#pragma unroll
    for (int i = 0; i < 4; ++i) {
        const int y = blockIdx.y * 32 + ty + i * 8;
        tile[ty + i * 8][tx] = W[(size_t)y * 1024 + x];
    }
    __syncthreads();
#pragma unroll
    for (int i = 0; i < 4; ++i) {
        const int yo = blockIdx.x * 32 + ty + i * 8;  // out row (= W col)
        const int xo = blockIdx.y * 32 + tx;          // out col (= W row)
        out[(size_t)yo * 1024 + xo] = f2bf(tile[tx][ty + i * 8]);
    }
}

__global__ void concat_bias(const float* __restrict__ bq, const float* __restrict__ bv,
                            float* __restrict__ bqv) {
    const int i = blockIdx.x * 256 + threadIdx.x;   // 0..2047
    bqv[i] = (i < 1024) ? bq[i] : bv[i - 1024];
}

// ---------- MFMA GEMM: C = A[M,K] * BT[N,K]^T + bias ----------
// LDS XOR-swizzled (SQ_LDS_BANK_CONFLICT=0 verified R2), staging pointers hoisted (R3).
// mode 0: fp32 store.  mode 1: fused QV epilogue (row-softmax*s -> qsOut | v -> vOut).
__global__ __launch_bounds__(256) void gemm_bt(
    const u16* __restrict__ A, const u16* __restrict__ BT,
    const float* __restrict__ bias, float* __restrict__ C,
    u16* __restrict__ qsOut, u16* __restrict__ vOut,
    int N, int K, int mode,
    long long Ab, long long Bb, long long Cb)
{
    __shared__ u16 As[128 * 64];
    __shared__ u16 Bs[128 * 64];
    const int t = threadIdx.x;
    const int w = t >> 6, l = t & 63;
    const int quad = l >> 4, lrow = l & 15;
    const int z = blockIdx.z;
    A  += (size_t)z * Ab;
    BT += (size_t)z * Bb;

    const int nbx = gridDim.x;
    int bx = blockIdx.x, by = blockIdx.y;
    if ((nbx & 7) == 0) {
        const int id = blockIdx.x + nbx * blockIdx.y;
        const int xcd = id & 7, j = id >> 3;
        const int xs = nbx >> 3;
        bx = xcd * xs + (j % xs);
        by = j / xs;
    }
    const int m0 = bx * 128;
    const int n0 = by * 128;
    const int wm = (w & 1) * 64, wn = (w >> 1) * 64;

    const int srow = t >> 3;
    const int scol_l = (t & 7) * 8;
    const int scol_g = ((t & 7) ^ (srow & 7)) * 8;

    const u16* ap[4];
    const u16* bp[4];
    u16* al[4];
    u16* bl[4];
#pragma unroll
    for (int p = 0; p < 4; ++p) {
        ap[p] = A  + (size_t)(m0 + p * 32 + srow) * K + scol_g;
        bp[p] = BT + (size_t)(n0 + p * 32 + srow) * K + scol_g;
        al[p] = &As[(p * 32 + srow) * 64 + scol_l];
        bl[p] = &Bs[(p * 32 + srow) * 64 + scol_l];
    }

    f4 acc[4][4] = {};
    const int swz = (quad ^ (lrow & 7)) << 3;

    for (int it = K >> 6; it > 0; --it) {
#pragma unroll
        for (int p = 0; p < 4; ++p) {
            GLD16(ap[p], al[p]);
            GLD16(bp[p], bl[p]);
            ap[p] += 64; bp[p] += 64;
        }
        __syncthreads();
#pragma unroll
        for (int kk = 0; kk < 2; ++kk) {
            const int koff = swz ^ (kk << 5);
            short8 a[4], b[4];
#pragma unroll
            for (int i = 0; i < 4; ++i)
                a[i] = *(const short8*)&As[(wm + i * 16 + lrow) * 64 + koff];
#pragma unroll
            for (int j = 0; j < 4; ++j)
                b[j] = *(const short8*)&Bs[(wn + j * 16 + lrow) * 64 + koff];
#pragma unroll
            for (int i = 0; i < 4; ++i)
#pragma unroll
                for (int j = 0; j < 4; ++j)
                    acc[i][j] = __builtin_amdgcn_mfma_f32_16x16x32_bf16(a[i], b[j], acc[i][j], 0, 0, 0);
        }
        __syncthreads();
    }

    const int colb = n0 + wn + lrow;
    const float b0 = bias[colb], b1 = bias[colb + 16], b2 = bias[colb + 32], b3 = bias[colb + 48];

    if (mode == 0) {
        C += (size_t)z * Cb;
#pragma unroll
        for (int i = 0; i < 4; ++i) {
            const int rbase = m0 + wm + i * 16 + quad * 4;
#pragma unroll
            for (int r = 0; r < 4; ++r) {
                float* cp = C + (size_t)(rbase + r) * N + colb;
                cp[0]  = acc[i][0][r] + b0;
                cp[16] = acc[i][1][r] + b1;
                cp[32] = acc[i][2][r] + b2;
                cp[48] = acc[i][3][r] + b3;
            }
        }
    } else {
        const bool isQ = (n0 + wn) < (N >> 1);   // wave-uniform
#pragma unroll
        for (int i = 0; i < 4; ++i) {
            const int rbase = m0 + wm + i * 16 + quad * 4;
#pragma unroll
            for (int r = 0; r < 4; ++r) {
                float v0 = acc[i][0][r] + b0;
                float v1 = acc[i][1][r] + b1;
                float v2 = acc[i][2][r] + b2;
                float v3 = acc[i][3][r] + b3;
                if (isQ) {
                    float m = fmaxf(fmaxf(v0, v1), fmaxf(v2, v3));
                    m = fmaxf(m, __shfl_xor(m, 1));
                    m = fmaxf(m, __shfl_xor(m, 2));
                    m = fmaxf(m, __shfl_xor(m, 4));
                    m = fmaxf(m, __shfl_xor(m, 8));
                    float e0 = __expf(v0 - m), e1 = __expf(v1 - m);
                    float e2 = __expf(v2 - m), e3 = __expf(v3 - m);
                    float sm = e0 + e1 + e2 + e3;
                    sm += __shfl_xor(sm, 1);
                    sm += __shfl_xor(sm, 2);
                    sm += __shfl_xor(sm, 4);
                    sm += __shfl_xor(sm, 8);
                    const float inv = SCALE_S / sm;
                    u16* qp = qsOut + (size_t)(rbase + r) * 1024 + colb;
                    qp[0]  = f2bf(e0 * inv);
                    qp[16] = f2bf(e1 * inv);
                    qp[32] = f2bf(e2 * inv);
                    qp[48] = f2bf(e3 * inv);
                } else {
                    u16* vp = vOut + (size_t)(rbase + r) * 1024 + (colb - 1024);
                    vp[0]  = f2bf(v0);
                    vp[16] = f2bf(v1);
                    vp[32] = f2bf(v2);
                    vp[48] = f2bf(v3);
                }
            }
        }
    }
}

// ---------- ctx partials via MFMA: Mpart[split][g][d][e] = sum_n exp(qs[n,d]) * v[n,e] ----
// Per (b,h): D = E^T V is a 64x64x4096 GEMM. Grid (64 g, 16 splits); block covers 256 n
// in 4 slabs of 64. Stage transposed bf16 tiles Et[d][n], Vt[e][n] (XOR-swizzled like
// gemm_bt); wave w computes output rows [16w,16w+16) over full K in-register -> 16
// partials/g, same Mpart/Zpart layout as before (ctx_norm unchanged).
__global__ __launch_bounds__(256) void ctx_mfma(
    const u16* __restrict__ qs, const u16* __restrict__ vb,
    float* __restrict__ Mpart, float* __restrict__ Zpart)
{
    __shared__ __align__(16) u16 Et[64 * 64];
    __shared__ __align__(16) u16 Vt[64 * 64];
    const int t = threadIdx.x;
    const int w = t >> 6, l = t & 63;
    const int quad = l >> 4, lrow = l & 15;
    const int g = blockIdx.x;          // b = g>>4, h = g&15
    const int split = blockIdx.y;      // 0..15
    const int b = g >> 4, h = g & 15;

    // staging role: rows n0,n0+1 at 8 d's
    const int n0 = (l & 31) * 2;
    const int d0 = w * 16 + (l >> 5) * 8;
    const size_t gbase = ((size_t)b * 4096 + (size_t)split * 256) * 1024 + h * 64 + d0;

    f4 acc[4] = {};
    float zl = 0.f;

    for (int slab = 0; slab < 4; ++slab) {
        const size_t ga = gbase + (size_t)(slab * 64 + n0) * 1024;
        us8 q8a = *(const us8*)(qs + ga);
        us8 q8b = *(const us8*)(qs + ga + 1024);
        us8 v8a = *(const us8*)(vb + ga);
        us8 v8b = *(const us8*)(vb + ga + 1024);
        unsigned epk[8], vpk[8];
#pragma unroll
        for (int j = 0; j < 8; ++j) {
            epk[j] = (unsigned)f2bf(__expf(bf2f((u16)q8a[j])))
                   | ((unsigned)f2bf(__expf(bf2f((u16)q8b[j]))) << 16);
            vpk[j] = (unsigned)(u16)v8a[j] | ((unsigned)(u16)v8b[j] << 16);
        }
        if (slab) __syncthreads();     // previous slab's reads done
#pragma unroll
        for (int j = 0; j < 8; ++j) {
            const int d = d0 + j;
            const int off = d * 64 + (((n0 >> 3) ^ (d & 7)) << 3) + (n0 & 7);
            *(unsigned*)&Et[off] = epk[j];
            *(unsigned*)&Vt[off] = vpk[j];
        }
        __syncthreads();
        // MFMA: wave w -> output rows [16w,16w+16), K=64 (2 kk of 32)
#pragma unroll
        for (int kk = 0; kk < 2; ++kk) {
            const int blk = ((kk * 4 + quad) ^ (lrow & 7)) << 3;
            short8 a = *(const short8*)&Et[(w * 16 + lrow) * 64 + blk];
            short8 bfr[4];
#pragma unroll
            for (int j = 0; j < 4; ++j)
                bfr[j] = *(const short8*)&Vt[(j * 16 + lrow) * 64 + blk];
#pragma unroll
            for (int j = 0; j < 4; ++j)
                acc[j] = __builtin_amdgcn_mfma_f32_16x16x32_bf16(a, bfr[j], acc[j], 0, 0, 0);
        }
        // Z partial: lane covers d = 16w + (l&15), n-range (l>>4)*16..+16
        {
            const int d = w * 16 + (l & 15);
            const int jb = (l >> 4) * 2;
            const short8 s0 = *(const short8*)&Et[d * 64 + ((jb ^ (d & 7)) << 3)];
            const short8 s1 = *(const short8*)&Et[d * 64 + (((jb + 1) ^ (d & 7)) << 3)];
#pragma unroll
            for (int j = 0; j < 8; ++j)
                zl += bf2f((u16)s0[j]) + bf2f((u16)s1[j]);
        }
    }

    // reduce Z across the 4 n-range lane groups
    zl += __shfl_xor(zl, 16);
    zl += __shfl_xor(zl, 32);
    if (l < 16)
        Zpart[((size_t)split * 64 + g) * 64 + w * 16 + l] = zl;

    // store acc: row m = 16w + quad*4 + r, col e = j*16 + lrow
    float* mp = Mpart + ((size_t)split * 64 + g) * 4096;
#pragma unroll
    for (int j = 0; j < 4; ++j)
#pragma unroll
        for (int r = 0; r < 4; ++r)
            mp[(w * 16 + quad * 4 + r) * 64 + j * 16 + lrow] = acc[j][r];
}

// ---------- reduce partials + normalize: ctx2[g][d][e] = s * sum M / sum Z ----------
__global__ __launch_bounds__(256) void ctx_norm(const float* __restrict__ Mpart,
                                                const float* __restrict__ Zpart,
                                                float* __restrict__ ctx2) {
    const int g = blockIdx.x, t = threadIdx.x;
    __shared__ float rz[64];
    if (t < 64) {
        float zsum = 0.f;
#pragma unroll
        for (int s = 0; s < 16; ++s) zsum += Zpart[((size_t)s * 64 + g) * 64 + t];
        rz[t] = SCALE_S / zsum;
    }
    __syncthreads();
    for (int idx = t; idx < 4096; idx += 256) {
        float m = 0.f;
#pragma unroll
        for (int s = 0; s < 16; ++s) m += Mpart[((size_t)s * 64 + g) * 4096 + idx];
        ctx2[(size_t)g * 4096 + idx] = m * rz[idx >> 6];
    }
}

// ---------- W'T_b[j][h*64+d] = sum_e WoT[j][h*64+e] * ctx2[b,h][d][e] ----------
__global__ __launch_bounds__(256) void woprime(const float* __restrict__ ctx2,
                                               const u16* __restrict__ WoT,
                                               u16* __restrict__ WopT) {
    __shared__ float ctxT[64 * 65];          // [e][d], padded
    __shared__ __align__(16) u16 wo[64 * 64];
    const int t = threadIdx.x;
    const int jt = blockIdx.x, h = blockIdx.y, b = blockIdx.z;
    const int g = b * 16 + h;
    for (int idx = t; idx < 4096; idx += 256) {
        const int d = idx >> 6, e = idx & 63;
        ctxT[e * 65 + d] = ctx2[(size_t)g * 4096 + idx];
    }
    const int j0 = jt * 64;
#pragma unroll
    for (int c = 0; c < 2; ++c) {
        const int ii = c * 256 + t;
        const int j = ii >> 3, c8 = ii & 7;
        *(us8*)&wo[j * 64 + c8 * 8] = *(const us8*)&WoT[(size_t)(j0 + j) * 1024 + h * 64 + c8 * 8];
    }
    __syncthreads();
    const int d = t & 63, w = t >> 6;
    float accj[16] = {};
    for (int eb = 0; eb < 8; ++eb) {
        float c8[8];
#pragma unroll
        for (int e = 0; e < 8; ++e) c8[e] = ctxT[(eb * 8 + e) * 65 + d];
#pragma unroll
        for (int jj = 0; jj < 16; ++jj) {
            us8 w8 = *(const us8*)&wo[(jj * 4 + w) * 64 + eb * 8];   // wave-uniform broadcast
#pragma unroll
            for (int e = 0; e < 8; ++e)
                accj[jj] += bf2f((u16)w8[e]) * c8[e];
        }
    }
#pragma unroll
    for (int jj = 0; jj < 16; ++jj)
        WopT[(size_t)b * 1048576 + (size_t)(j0 + jj * 4 + w) * 1024 + h * 64 + d] = f2bf(accj[jj]);
}

// ---------- launch ----------
extern "C" void kernel_launch(void* const* d_in, const int* in_sizes, int n_in,
                              void* d_out, int out_size, void* d_ws, size_t ws_size,
                              hipStream_t stream)
{
    const float* x  = (const float*)d_in[0];
    const float* Wq = (const float*)d_in[1];
    const float* bq = (const float*)d_in[2];
    // d_in[3]=Wk, d_in[4]=bk : dead code in the reference, skipped
    const float* Wv = (const float*)d_in[5];
    const float* bv = (const float*)d_in[6];
    const float* Wo = (const float*)d_in[7];
    const float* bo = (const float*)d_in[8];
    float* out = (float*)d_out;

    char* ws = (char*)d_ws;
    size_t o = 0;
    auto alloc = [&](size_t bytes) { char* p = ws + o; o = (o + bytes + 255) & ~(size_t)255; return p; };
    u16*   x_bf  = (u16*)  alloc(16384ull * 1024 * 2);   // 32 MB (dead after GEMM1 -> reused as Mpart)
    u16*   WqvT  = (u16*)  alloc(2048ull * 1024 * 2);    //  4 MB
    u16*   WoT   = (u16*)  alloc(1024ull * 1024 * 2);    //  2 MB
    float* bqv   = (float*)alloc(2048ull * 4);
    u16*   qs    = (u16*)  alloc(16384ull * 1024 * 2);   // 32 MB
    u16*   vbuf  = (u16*)  alloc(16384ull * 1024 * 2);   // 32 MB
    float* Zpart = (float*)alloc(16ull * 64 * 64 * 4);
    float* ctx2  = (float*)alloc(64ull * 4096 * 4);      //  1 MB
    u16*   WopT  = (u16*)  alloc(4ull * 1024 * 1024 * 2);//  8 MB
    float* Mpart = (float*)x_bf;                         // 16 MB alias (x_bf dead by then)
    (void)ws_size; (void)in_sizes; (void)n_in; (void)out_size;

    convert_f32_bf16<<<8192, 256, 0, stream>>>(x, x_bf);
    transpose_convert3<<<dim3(32, 32, 3), dim3(32, 8), 0, stream>>>(Wq, Wv, Wo, WqvT, WoT);
    concat_bias<<<8, 256, 0, stream>>>(bq, bv, bqv);

    // QV projection + fused first softmax epilogue
    gemm_bt<<<dim3(128, 16, 1), 256, 0, stream>>>(x_bf, WqvT, bqv, nullptr, qs, vbuf,
                                                  2048, 1024, 1, 0, 0, 0);
    // second softmax (over seq) folded into MFMA-based weighted-sum partials
    ctx_mfma<<<dim3(64, 16), 256, 0, stream>>>(qs, vbuf, Mpart, Zpart);
    ctx_norm<<<64, 256, 0, stream>>>(Mpart, Zpart, ctx2);
    // W'_b = blockdiag(ctx2_b) @ Wo
    woprime<<<dim3(16, 16, 4), 256, 0, stream>>>(ctx2, WoT, WopT);
    // out = qs @ W'_b + bo
    gemm_bt<<<dim3(32, 8, 4), 256, 0, stream>>>(qs, WopT, bo, out, nullptr, nullptr,
                                                1024, 1024, 0,
                                                4096ll * 1024, 1024ll * 1024, 4096ll * 1024);
}

// Round 5
// 316.246 us; speedup vs baseline: 1.2578x; 1.0318x over previous
//
#include <hip/hip_runtime.h>

typedef unsigned short u16;
typedef __attribute__((ext_vector_type(8))) short short8;   // 8 bf16 (4 VGPRs) - MFMA A/B frag
typedef __attribute__((ext_vector_type(4))) float f4;       // MFMA C/D frag
typedef __attribute__((ext_vector_type(8))) unsigned short us8;

// ---------- helpers ----------
__device__ __forceinline__ u16 f2bf(float f) {              // RNE fp32 -> bf16
    unsigned u = __float_as_uint(f);
    u += 0x7FFFu + ((u >> 16) & 1u);
    return (u16)(u >> 16);
}
__device__ __forceinline__ float bf2f(u16 h) {
    return __uint_as_float(((unsigned)h) << 16);
}

#define GLD16(gp, lp) __builtin_amdgcn_global_load_lds( \
    (const __attribute__((address_space(1))) void*)(gp), \
    (__attribute__((address_space(3))) void*)(lp), 16, 0, 0)

// s = (d_head^0.5)^(-0.25) = 8^(-0.25)
#define SCALE_S 0.594603557501360533f

// ---------- fp32 -> bf16 (8 elems/thread) ----------
__global__ __launch_bounds__(256) void convert_f32_bf16(const float* __restrict__ in,
                                                        u16* __restrict__ out) {
    const size_t i = (size_t)blockIdx.x * 256 + threadIdx.x;
    const float4* p = (const float4*)in + i * 2;
    float4 a = p[0], b = p[1];
    us8 r;
    r[0] = f2bf(a.x); r[1] = f2bf(a.y); r[2] = f2bf(a.z); r[3] = f2bf(a.w);
    r[4] = f2bf(b.x); r[5] = f2bf(b.y); r[6] = f2bf(b.z); r[7] = f2bf(b.w);
    *(us8*)(out + i * 8) = r;
}

// ---------- transpose + convert x3: out[n][k] = bf16(W[k][n]), 1024x1024 ----------
__global__ __launch_bounds__(256) void transpose_convert3(
    const float* __restrict__ Wq, const float* __restrict__ Wv, const float* __restrict__ Wo,
    u16* __restrict__ WqvT, u16* __restrict__ WoT) {
    const float* W; u16* out;
    if (blockIdx.z == 0)      { W = Wq; out = WqvT; }
    else if (blockIdx.z == 1) { W = Wv; out = WqvT + 1024 * 1024; }
    else                      { W = Wo; out = WoT; }
    __shared__ float tile[32][33];
    const int tx = threadIdx.x, ty = threadIdx.y;   // 32 x 8
    const int x = blockIdx.x * 32 + tx;
#pragma unroll
    for (int i = 0; i < 4; ++i) {
        const int y = blockIdx.y * 32 + ty + i * 8;
        tile[ty + i * 8][tx] = W[(size_t)y * 1024 + x];
    }
    __syncthreads();
#pragma unroll
    for (int i = 0; i < 4; ++i) {
        const int yo = blockIdx.x * 32 + ty + i * 8;  // out row (= W col)
        const int xo = blockIdx.y * 32 + tx;          // out col (= W row)
        out[(size_t)yo * 1024 + xo] = f2bf(tile[tx][ty + i * 8]);
    }
}

__global__ void concat_bias(const float* __restrict__ bq, const float* __restrict__ bv,
                            float* __restrict__ bqv) {
    const int i = blockIdx.x * 256 + threadIdx.x;   // 0..2047
    bqv[i] = (i < 1024) ? bq[i] : bv[i - 1024];
}

// ---------- GEMM1: [x] @ [WqT;WvT]^T + bias, fused first-softmax epilogue ----------
// LDS XOR-swizzled (SQ_LDS_BANK_CONFLICT=0, R2), staging pointers hoisted (R3).
__global__ __launch_bounds__(256) void gemm_qv(
    const u16* __restrict__ A, const u16* __restrict__ BT,
    const float* __restrict__ bias,
    u16* __restrict__ qsOut, u16* __restrict__ vOut)
{
    const int N = 2048, K = 1024;
    __shared__ u16 As[128 * 64];
    __shared__ u16 Bs[128 * 64];
    const int t = threadIdx.x;
    const int w = t >> 6, l = t & 63;
    const int quad = l >> 4, lrow = l & 15;

    const int nbx = gridDim.x;
    int bx = blockIdx.x, by = blockIdx.y;
    {
        const int id = blockIdx.x + nbx * blockIdx.y;
        const int xcd = id & 7, j = id >> 3;
        const int xs = nbx >> 3;
        bx = xcd * xs + (j % xs);
        by = j / xs;
    }
    const int m0 = bx * 128;
    const int n0 = by * 128;
    const int wm = (w & 1) * 64, wn = (w >> 1) * 64;

    const int srow = t >> 3;
    const int scol_l = (t & 7) * 8;
    const int scol_g = ((t & 7) ^ (srow & 7)) * 8;

    const u16* ap[4];
    const u16* bp[4];
    u16* al[4];
    u16* bl[4];
#pragma unroll
    for (int p = 0; p < 4; ++p) {
        ap[p] = A  + (size_t)(m0 + p * 32 + srow) * K + scol_g;
        bp[p] = BT + (size_t)(n0 + p * 32 + srow) * K + scol_g;
        al[p] = &As[(p * 32 + srow) * 64 + scol_l];
        bl[p] = &Bs[(p * 32 + srow) * 64 + scol_l];
    }

    f4 acc[4][4] = {};
    const int swz = (quad ^ (lrow & 7)) << 3;

    for (int it = K >> 6; it > 0; --it) {
#pragma unroll
        for (int p = 0; p < 4; ++p) {
            GLD16(ap[p], al[p]);
            GLD16(bp[p], bl[p]);
            ap[p] += 64; bp[p] += 64;
        }
        __syncthreads();
#pragma unroll
        for (int kk = 0; kk < 2; ++kk) {
            const int koff = swz ^ (kk << 5);
            short8 a[4], b[4];
#pragma unroll
            for (int i = 0; i < 4; ++i)
                a[i] = *(const short8*)&As[(wm + i * 16 + lrow) * 64 + koff];
#pragma unroll
            for (int j = 0; j < 4; ++j)
                b[j] = *(const short8*)&Bs[(wn + j * 16 + lrow) * 64 + koff];
#pragma unroll
            for (int i = 0; i < 4; ++i)
#pragma unroll
                for (int j = 0; j < 4; ++j)
                    acc[i][j] = __builtin_amdgcn_mfma_f32_16x16x32_bf16(a[i], b[j], acc[i][j], 0, 0, 0);
        }
        __syncthreads();
    }

    const int colb = n0 + wn + lrow;
    const float b0 = bias[colb], b1 = bias[colb + 16], b2 = bias[colb + 32], b3 = bias[colb + 48];
    const bool isQ = (n0 + wn) < (N >> 1);   // wave-uniform
#pragma unroll
    for (int i = 0; i < 4; ++i) {
        const int rbase = m0 + wm + i * 16 + quad * 4;
#pragma unroll
        for (int r = 0; r < 4; ++r) {
            float v0 = acc[i][0][r] + b0;
            float v1 = acc[i][1][r] + b1;
            float v2 = acc[i][2][r] + b2;
            float v3 = acc[i][3][r] + b3;
            if (isQ) {
                float m = fmaxf(fmaxf(v0, v1), fmaxf(v2, v3));
                m = fmaxf(m, __shfl_xor(m, 1));
                m = fmaxf(m, __shfl_xor(m, 2));
                m = fmaxf(m, __shfl_xor(m, 4));
                m = fmaxf(m, __shfl_xor(m, 8));
                float e0 = __expf(v0 - m), e1 = __expf(v1 - m);
                float e2 = __expf(v2 - m), e3 = __expf(v3 - m);
                float sm = e0 + e1 + e2 + e3;
                sm += __shfl_xor(sm, 1);
                sm += __shfl_xor(sm, 2);
                sm += __shfl_xor(sm, 4);
                sm += __shfl_xor(sm, 8);
                const float inv = SCALE_S / sm;
                u16* qp = qsOut + (size_t)(rbase + r) * 1024 + colb;
                qp[0]  = f2bf(e0 * inv);
                qp[16] = f2bf(e1 * inv);
                qp[32] = f2bf(e2 * inv);
                qp[48] = f2bf(e3 * inv);
            } else {
                u16* vp = vOut + (size_t)(rbase + r) * 1024 + (colb - 1024);
                vp[0]  = f2bf(v0);
                vp[16] = f2bf(v1);
                vp[32] = f2bf(v2);
                vp[48] = f2bf(v3);
            }
        }
    }
}

// ---------- GEMM3: out[z] = qs[z] @ WopT[z]^T + bo (fp32 store) ----------
__global__ __launch_bounds__(256) void gemm_out(
    const u16* __restrict__ A, const u16* __restrict__ BT,
    const float* __restrict__ bias, float* __restrict__ C)
{
    const int N = 1024, K = 1024;
    __shared__ u16 As[128 * 64];
    __shared__ u16 Bs[128 * 64];
    const int t = threadIdx.x;
    const int w = t >> 6, l = t & 63;
    const int quad = l >> 4, lrow = l & 15;
    const int z = blockIdx.z;
    A  += (size_t)z * (4096 * 1024);
    BT += (size_t)z * (1024 * 1024);
    C  += (size_t)z * (4096 * 1024);

    const int nbx = gridDim.x;
    int bx = blockIdx.x, by = blockIdx.y;
    {
        const int id = blockIdx.x + nbx * blockIdx.y;
        const int xcd = id & 7, j = id >> 3;
        const int xs = nbx >> 3;
        bx = xcd * xs + (j % xs);
        by = j / xs;
    }
    const int m0 = bx * 128;
    const int n0 = by * 128;
    const int wm = (w & 1) * 64, wn = (w >> 1) * 64;

    const int srow = t >> 3;
    const int scol_l = (t & 7) * 8;
    const int scol_g = ((t & 7) ^ (srow & 7)) * 8;

    const u16* ap[4];
    const u16* bp[4];
    u16* al[4];
    u16* bl[4];
#pragma unroll
    for (int p = 0; p < 4; ++p) {
        ap[p] = A  + (size_t)(m0 + p * 32 + srow) * K + scol_g;
        bp[p] = BT + (size_t)(n0 + p * 32 + srow) * K + scol_g;
        al[p] = &As[(p * 32 + srow) * 64 + scol_l];
        bl[p] = &Bs[(p * 32 + srow) * 64 + scol_l];
    }

    f4 acc[4][4] = {};
    const int swz = (quad ^ (lrow & 7)) << 3;

    for (int it = K >> 6; it > 0; --it) {
#pragma unroll
        for (int p = 0; p < 4; ++p) {
            GLD16(ap[p], al[p]);
            GLD16(bp[p], bl[p]);
            ap[p] += 64; bp[p] += 64;
        }
        __syncthreads();
#pragma unroll
        for (int kk = 0; kk < 2; ++kk) {
            const int koff = swz ^ (kk << 5);
            short8 a[4], b[4];
#pragma unroll
            for (int i = 0; i < 4; ++i)
                a[i] = *(const short8*)&As[(wm + i * 16 + lrow) * 64 + koff];
#pragma unroll
            for (int j = 0; j < 4; ++j)
                b[j] = *(const short8*)&Bs[(wn + j * 16 + lrow) * 64 + koff];
#pragma unroll
            for (int i = 0; i < 4; ++i)
#pragma unroll
                for (int j = 0; j < 4; ++j)
                    acc[i][j] = __builtin_amdgcn_mfma_f32_16x16x32_bf16(a[i], b[j], acc[i][j], 0, 0, 0);
        }
        __syncthreads();
    }

    const int colb = n0 + wn + lrow;
    const float b0 = bias[colb], b1 = bias[colb + 16], b2 = bias[colb + 32], b3 = bias[colb + 48];
#pragma unroll
    for (int i = 0; i < 4; ++i) {
        const int rbase = m0 + wm + i * 16 + quad * 4;
#pragma unroll
        for (int r = 0; r < 4; ++r) {
            float* cp = C + (size_t)(rbase + r) * N + colb;
            cp[0]  = acc[i][0][r] + b0;
            cp[16] = acc[i][1][r] + b1;
            cp[32] = acc[i][2][r] + b2;
            cp[48] = acc[i][3][r] + b3;
        }
    }
}

// ---------- ctx partials via MFMA: Mpart[split][g][d][e] = sum_n exp(qs[n,d]) * v[n,e] ----
// Double-buffered Et/Vt, ONE barrier per 64-row slab:
//   iter s: write buf[s&1] -> sync -> MFMA-read buf[s&1].
//   Hazards: write buf[(s+1)&1] (iter s+1) vs MFMA-read of same buf (iter s-1): separated
//   by iter s's sync. MFMA-read buf[s&1] (iter s) vs write of same buf (iter s+2):
//   separated by iter s+1's sync. QED one sync/iter.
// Global us8 loads for slab s+1 issued before slab s's write/sync/MFMA (full-slab
// latency hiding). Z accumulated in registers during exp (no LDS re-read).
__global__ __launch_bounds__(256) void ctx_mfma(
    const u16* __restrict__ qs, const u16* __restrict__ vb,
    float* __restrict__ Mpart, float* __restrict__ Zpart)
{
    __shared__ __align__(16) u16 Et[2][64 * 64];
    __shared__ __align__(16) u16 Vt[2][64 * 64];
    const int t = threadIdx.x;
    const int w = t >> 6, l = t & 63;
    const int quad = l >> 4, lrow = l & 15;
    const int g = blockIdx.x;          // b = g>>4, h = g&15
    const int split = blockIdx.y;      // 0..15
    const int b = g >> 4, h = g & 15;

    const int n0 = (l & 31) * 2;       // rows n0, n0+1 within slab
    const int d0 = w * 16 + (l >> 5) * 8;
    const u16* qp = qs + ((size_t)b * 4096 + (size_t)split * 256 + n0) * 1024 + h * 64 + d0;
    const u16* vp = vb + ((size_t)b * 4096 + (size_t)split * 256 + n0) * 1024 + h * 64 + d0;

    f4 acc[4] = {};
    float zacc[8] = {};

    us8 q8a = *(const us8*)qp;
    us8 q8b = *(const us8*)(qp + 1024);
    us8 v8a = *(const us8*)vp;
    us8 v8b = *(const us8*)(vp + 1024);

    for (int slab = 0; slab < 4; ++slab) {
        unsigned epk[8], vpk[8];
#pragma unroll
        for (int j = 0; j < 8; ++j) {
            float ea = __expf(bf2f((u16)q8a[j]));
            float eb = __expf(bf2f((u16)q8b[j]));
            zacc[j] += ea + eb;
            epk[j] = (unsigned)f2bf(ea) | ((unsigned)f2bf(eb) << 16);
            vpk[j] = (unsigned)(u16)v8a[j] | ((unsigned)(u16)v8b[j] << 16);
        }
        if (slab < 3) {                // prefetch next slab (overlaps sync+MFMA below)
            qp += 64 * 1024; vp += 64 * 1024;
            q8a = *(const us8*)qp;  q8b = *(const us8*)(qp + 1024);
            v8a = *(const us8*)vp;  v8b = *(const us8*)(vp + 1024);
        }
        u16* et = Et[slab & 1];
        u16* vt = Vt[slab & 1];
#pragma unroll
        for (int j = 0; j < 8; ++j) {
            const int d = d0 + j;
            const int off = d * 64 + (((n0 >> 3) ^ (d & 7)) << 3) + (n0 & 7);
            *(unsigned*)&et[off] = epk[j];
            *(unsigned*)&vt[off] = vpk[j];
        }
        __syncthreads();
#pragma unroll
        for (int kk = 0; kk < 2; ++kk) {
            const int blk = ((kk * 4 + quad) ^ (lrow & 7)) << 3;
            short8 a = *(const short8*)&et[(w * 16 + lrow) * 64 + blk];
#pragma unroll
            for (int j = 0; j < 4; ++j) {
                short8 bfr = *(const short8*)&vt[(j * 16 + lrow) * 64 + blk];
                acc[j] = __builtin_amdgcn_mfma_f32_16x16x32_bf16(a, bfr, acc[j], 0, 0, 0);
            }
        }
    }

    // Z: butterfly within each 32-lane half (all lanes of a half share d0-range)
#pragma unroll
    for (int j = 0; j < 8; ++j) {
        zacc[j] += __shfl_xor(zacc[j], 1);
        zacc[j] += __shfl_xor(zacc[j], 2);
        zacc[j] += __shfl_xor(zacc[j], 4);
        zacc[j] += __shfl_xor(zacc[j], 8);
        zacc[j] += __shfl_xor(zacc[j], 16);
    }
    if ((l & 31) == 0) {
        float* zp = Zpart + ((size_t)split * 64 + g) * 64 + d0;
#pragma unroll
        for (int j = 0; j < 8; ++j) zp[j] = zacc[j];
    }

    // store acc: row m(d) = 16w + quad*4 + r, col e = j*16 + lrow
    float* mp = Mpart + ((size_t)split * 64 + g) * 4096;
#pragma unroll
    for (int j = 0; j < 4; ++j)
#pragma unroll
        for (int r = 0; r < 4; ++r)
            mp[(w * 16 + quad * 4 + r) * 64 + j * 16 + lrow] = acc[j][r];
}

// ---------- reduce partials + normalize: ctx2[g][d][e] = s * sum M / sum Z ----------
__global__ __launch_bounds__(256) void ctx_norm(const float* __restrict__ Mpart,
                                                const float* __restrict__ Zpart,
                                                float* __restrict__ ctx2) {
    const int g = blockIdx.x, t = threadIdx.x;
    __shared__ float rz[64];
    if (t < 64) {
        float zsum = 0.f;
#pragma unroll
        for (int s = 0; s < 16; ++s) zsum += Zpart[((size_t)s * 64 + g) * 64 + t];
        rz[t] = SCALE_S / zsum;
    }
    __syncthreads();
    for (int idx = t; idx < 4096; idx += 256) {
        float m = 0.f;
#pragma unroll
        for (int s = 0; s < 16; ++s) m += Mpart[((size_t)s * 64 + g) * 4096 + idx];
        ctx2[(size_t)g * 4096 + idx] = m * rz[idx >> 6];
    }
}

// ---------- W'T_b[j][h*64+d] = sum_e WoT[j][h*64+e] * ctx2[b,h][d][e] ----------
__global__ __launch_bounds__(256) void woprime(const float* __restrict__ ctx2,
                                               const u16* __restrict__ WoT,
                                               u16* __restrict__ WopT) {
    __shared__ float ctxT[64 * 65];          // [e][d], padded
    __shared__ __align__(16) u16 wo[64 * 64];
    const int t = threadIdx.x;
    const int jt = blockIdx.x, h = blockIdx.y, b = blockIdx.z;
    const int g = b * 16 + h;
    for (int idx = t; idx < 4096; idx += 256) {
        const int d = idx >> 6, e = idx & 63;
        ctxT[e * 65 + d] = ctx2[(size_t)g * 4096 + idx];
    }
    const int j0 = jt * 64;
#pragma unroll
    for (int c = 0; c < 2; ++c) {
        const int ii = c * 256 + t;
        const int j = ii >> 3, c8 = ii & 7;
        *(us8*)&wo[j * 64 + c8 * 8] = *(const us8*)&WoT[(size_t)(j0 + j) * 1024 + h * 64 + c8 * 8];
    }
    __syncthreads();
    const int d = t & 63, w = t >> 6;
    float accj[16] = {};
    for (int eb = 0; eb < 8; ++eb) {
        float c8[8];
#pragma unroll
        for (int e = 0; e < 8; ++e) c8[e] = ctxT[(eb * 8 + e) * 65 + d];
#pragma unroll
        for (int jj = 0; jj < 16; ++jj) {
            us8 w8 = *(const us8*)&wo[(jj * 4 + w) * 64 + eb * 8];   // wave-uniform broadcast
#pragma unroll
            for (int e = 0; e < 8; ++e)
                accj[jj] += bf2f((u16)w8[e]) * c8[e];
        }
    }
#pragma unroll
    for (int jj = 0; jj < 16; ++jj)
        WopT[(size_t)b * 1048576 + (size_t)(j0 + jj * 4 + w) * 1024 + h * 64 + d] = f2bf(accj[jj]);
}

// ---------- launch ----------
extern "C" void kernel_launch(void* const* d_in, const int* in_sizes, int n_in,
                              void* d_out, int out_size, void* d_ws, size_t ws_size,
                              hipStream_t stream)
{
    const float* x  = (const float*)d_in[0];
    const float* Wq = (const float*)d_in[1];
    const float* bq = (const float*)d_in[2];
    // d_in[3]=Wk, d_in[4]=bk : dead code in the reference, skipped
    const float* Wv = (const float*)d_in[5];
    const float* bv = (const float*)d_in[6];
    const float* Wo = (const float*)d_in[7];
    const float* bo = (const float*)d_in[8];
    float* out = (float*)d_out;

    char* ws = (char*)d_ws;
    size_t o = 0;
    auto alloc = [&](size_t bytes) { char* p = ws + o; o = (o + bytes + 255) & ~(size_t)255; return p; };
    u16*   x_bf  = (u16*)  alloc(16384ull * 1024 * 2);   // 32 MB (dead after GEMM1 -> reused as Mpart)
    u16*   WqvT  = (u16*)  alloc(2048ull * 1024 * 2);    //  4 MB
    u16*   WoT   = (u16*)  alloc(1024ull * 1024 * 2);    //  2 MB
    float* bqv   = (float*)alloc(2048ull * 4);
    u16*   qs    = (u16*)  alloc(16384ull * 1024 * 2);   // 32 MB
    u16*   vbuf  = (u16*)  alloc(16384ull * 1024 * 2);   // 32 MB
    float* Zpart = (float*)alloc(16ull * 64 * 64 * 4);
    float* ctx2  = (float*)alloc(64ull * 4096 * 4);      //  1 MB
    u16*   WopT  = (u16*)  alloc(4ull * 1024 * 1024 * 2);//  8 MB
    float* Mpart = (float*)x_bf;                         // 16 MB alias (x_bf dead by then)
    (void)ws_size; (void)in_sizes; (void)n_in; (void)out_size;

    convert_f32_bf16<<<8192, 256, 0, stream>>>(x, x_bf);
    transpose_convert3<<<dim3(32, 32, 3), dim3(32, 8), 0, stream>>>(Wq, Wv, Wo, WqvT, WoT);
    concat_bias<<<8, 256, 0, stream>>>(bq, bv, bqv);

    // QV projection + fused first softmax epilogue
    gemm_qv<<<dim3(128, 16), 256, 0, stream>>>(x_bf, WqvT, bqv, qs, vbuf);
    // second softmax (over seq) folded into MFMA-based weighted-sum partials
    ctx_mfma<<<dim3(64, 16), 256, 0, stream>>>(qs, vbuf, Mpart, Zpart);
    ctx_norm<<<64, 256, 0, stream>>>(Mpart, Zpart, ctx2);
    // W'_b = blockdiag(ctx2_b) @ Wo
    woprime<<<dim3(16, 16, 4), 256, 0, stream>>>(ctx2, WoT, WopT);
    // out = qs @ W'_b + bo
    gemm_out<<<dim3(32, 8, 4), 256, 0, stream>>>(qs, WopT, bo, out);
}